// Round 6
// baseline (102.721 us; speedup 1.0000x reference)
//
#include <hip/hip_runtime.h>
#include <math.h>

// Problem constants (fixed by setup_inputs)
#define NB 16
#define NT 4096
#define NC 64
#define NS 5
#define NH 32

#define TTILE 64
#define RMX 56
#define PN (TTILE + 2*RMX)   // 176 staged t-positions per tile

// tap table segment offsets: radii {10,16,24,36,56} -> lengths {21,33,49,73,113}
#define OFF0 0
#define OFF1 21
#define OFF2 54
#define OFF3 103
#define OFF4 176
#define NTAPS 289

#define NFRAG 13            // K-steps total: 2+2+2+3+4
#define SXT_LD 184          // bf16 elements per channel row

// MLP weight-table (z, logvar) -> 4 softmax weights (5th = 1 - sum)
// layout: [vi][zi], cell = 16B {w0..3 fp16 @ (zi,vi) | w0..3 fp16 @ (zi,vi+1)}
// bilinear corners = cells (vi,zi) and (vi,zi+1): ADJACENT 16B -> same cache line
#define NZ 512
#define NV 256
#define ZMINF (-4.0f)
#define VMINF (-14.0f)
#define ZSCLF (511.0f / 8.0f)
#define VSCLF (255.0f / 18.0f)
#define FRAG_BYTES 16384
#define TABLE_BYTES ((size_t)NZ * NV * 16)
#define WS_NEED (FRAG_BYTES + TABLE_BYTES)

typedef __attribute__((ext_vector_type(8))) short bf16x8;
typedef __attribute__((ext_vector_type(4))) float f32x4;

__device__ __forceinline__ unsigned short f2b(float f) {
    unsigned int u = __float_as_uint(f);
    unsigned int r = (u + 0x7fffu + ((u >> 16) & 1u)) >> 16;   // RNE
    return (unsigned short)r;
}
__device__ __forceinline__ float hlo(unsigned int u) {
    union { unsigned int u_; _Float16 h[2]; } t; t.u_ = u; return (float)t.h[0];
}
__device__ __forceinline__ float hhi(unsigned int u) {
    union { unsigned int u_; _Float16 h[2]; } t; t.u_ = u; return (float)t.h[1];
}
__device__ __forceinline__ unsigned int packh2(float a, float b) {
    union { unsigned int u_; _Float16 h[2]; } t;
    t.h[0] = (_Float16)a; t.h[1] = (_Float16)b; return t.u_;
}

// Abramowitz-Stegun 7.1.26, |err| <= 1.5e-7, branchless, no libm.
__device__ __forceinline__ float fast_erf(float x) {
    const float ax = fabsf(x);
    const float t = __fdividef(1.0f, fmaf(0.3275911f, ax, 1.0f));
    float p = fmaf(t, 1.061405429f, -1.453152027f);
    p = fmaf(t, p, 1.421413741f);
    p = fmaf(t, p, -0.284496736f);
    p = fmaf(t, p, 0.254829592f);
    p *= t;
    const float e = __expf(-ax * ax);
    const float r = fmaf(-p, e, 1.0f);
    return copysignf(r, x);
}

// exact-MLP softmax weights (fast-erf flavor): table build + rare slow path
__device__ __forceinline__ void mlp_w_fast(
    float z, float lv,
    const float* __restrict__ W1, const float* __restrict__ b1,
    const float* __restrict__ W2, const float* __restrict__ b2,
    float* __restrict__ wout)
{
    float l0 = b2[0], l1 = b2[1], l2 = b2[2], l3 = b2[3], l4 = b2[4];
    #pragma unroll 4
    for (int j = 0; j < NH; ++j) {
        const float a = fmaf(z, W1[2 * j], fmaf(lv, W1[2 * j + 1], b1[j]));
        const float g = 0.5f * a * (1.0f + fast_erf(a * 0.70710678118654752f));
        l0 = fmaf(g, W2[j],          l0);
        l1 = fmaf(g, W2[NH + j],     l1);
        l2 = fmaf(g, W2[2 * NH + j], l2);
        l3 = fmaf(g, W2[3 * NH + j], l3);
        l4 = fmaf(g, W2[4 * NH + j], l4);
    }
    const float sc = 1.4285714285714286f;
    const float mx = fmaxf(fmaxf(fmaxf(l0, l1), fmaxf(l2, l3)), l4);
    const float e0 = __expf((l0 - mx) * sc);
    const float e1 = __expf((l1 - mx) * sc);
    const float e2 = __expf((l2 - mx) * sc);
    const float e3 = __expf((l3 - mx) * sc);
    const float e4 = __expf((l4 - mx) * sc);
    const float rd = __fdividef(1.0f, e0 + e1 + e2 + e3 + e4);
    wout[0] = e0 * rd; wout[1] = e1 * rd; wout[2] = e2 * rd;
    wout[3] = e3 * rd; wout[4] = e4 * rd;
}

// ---------------- single init launch: block 0 -> A-frags; blocks 1.. -> LUT ----------------
__global__ void init_all_kernel(
    const float* __restrict__ W1, const float* __restrict__ b1,
    const float* __restrict__ W2, const float* __restrict__ b2,
    unsigned short* __restrict__ afr, unsigned int* __restrict__ tbl, int build_tbl)
{
    const int tid = threadIdx.x;
    if (blockIdx.x == 0) {
        __shared__ float raw[NTAPS];
        __shared__ float invs[NS];
        const int offs[6] = {OFF0, OFF1, OFF2, OFF3, OFF4, NTAPS};
        const float sig[NS] = {2.5f, 4.0f, 6.0f, 9.0f, 14.0f};
        const int RR[NS] = {10, 16, 24, 36, 56};
        for (int i = tid; i < NTAPS; i += blockDim.x) {
            int s = 0;
            #pragma unroll
            for (int k = 1; k < NS; ++k) if (i >= offs[k]) s = k;
            const int j = i - offs[s] - RR[s];
            const float u = (float)j / sig[s];
            raw[i] = __expf(-0.5f * u * u);
        }
        __syncthreads();
        if (tid < NS) {
            float sum = 0.f;
            for (int i = offs[tid]; i < offs[tid + 1]; ++i) sum += raw[i];
            invs[tid] = 1.0f / (sum + 1e-12f);
        }
        __syncthreads();
        const int fbase6[6] = {0, 2, 4, 6, 9, 13};
        const int RA[NS] = {16, 16, 24, 40, 56};
        for (int idx = tid; idx < NFRAG * 64 * 8; idx += blockDim.x) {
            const int f = idx >> 9;
            const int lane = (idx >> 3) & 63;
            const int e = idx & 7;
            int s = 0;
            #pragma unroll
            for (int k = 1; k < NS; ++k) if (f >= fbase6[k]) s = k;
            const int kk = f - fbase6[s];
            const int r = lane & 15;
            const int g = lane >> 4;
            const int j = 32 * kk + 8 * g + e - RA[s] - r;
            float v = 0.f;
            if (j >= -RR[s] && j <= RR[s]) v = raw[offs[s] + j + RR[s]] * invs[s];
            afr[idx] = f2b(v);
        }
    } else if (build_tbl) {
        const int idx = (blockIdx.x - 1) * 256 + tid;   // zi*NV + vi (compute grid)
        const int zi = idx / NV, vi = idx % NV;
        const float z  = ZMINF + (float)zi * (8.0f / 511.0f);
        const float lv = VMINF + (float)vi * (18.0f / 255.0f);
        float w[5];
        mlp_w_fast(z, lv, W1, b1, W2, b2, w);
        const unsigned int p01 = packh2(w[0], w[1]);
        const unsigned int p23 = packh2(w[2], w[3]);
        uint2 p = {p01, p23};
        // storage layout [vi][zi]: cell c(vi,zi) = {w @ (zi,vi) | w @ (zi,vi+1)}
        *reinterpret_cast<uint2*>(tbl + ((size_t)vi * NZ + zi) * 4) = p;          // own lo
        if (vi > 0)
            *reinterpret_cast<uint2*>(tbl + ((size_t)(vi - 1) * NZ + zi) * 4 + 2) = p; // row below's hi
        if (vi == NV - 1)
            *reinterpret_cast<uint2*>(tbl + ((size_t)vi * NZ + zi) * 4 + 2) = p;       // self hi (clamp)
    }
}

// ---------------- fused main kernel ----------------
template<bool SLOW>
__global__ __launch_bounds__(256, 4) void fused6_kernel(
    const float* __restrict__ x,  const float* __restrict__ W1,
    const float* __restrict__ b1, const float* __restrict__ W2,
    const float* __restrict__ b2, const uint4* __restrict__ afr4,
    const uint4* __restrict__ tb4, float* __restrict__ out)
{
    __shared__ __align__(16) short sxT[64 * SXT_LD];   // bf16 [c][t], 23552 B (only LDS)

    const int blk = blockIdx.x;
    const int b  = blk >> 6;              // NT/TTILE = 64
    const int t0 = (blk & 63) * TTILE;
    const float* xb = x + (size_t)b * NT * NC;
    const int tid = threadIdx.x;

    // ---- stage sxT (bf16 [c][t], reflect-padded), permuted kc (4-way banks) ----
    for (int idx = tid; idx < 44 * 16; idx += 256) {
        const int p4 = idx >> 4;
        const int l  = idx & 15;
        const int c4 = l << 2;
        float vv[4][4];
        #pragma unroll
        for (int k = 0; k < 4; ++k) {
            int gg = t0 - RMX + 4 * p4 + k;
            if (gg < 0) gg = -gg;
            if (gg >= NT) gg = 2 * NT - 2 - gg;
            const float4 v = *reinterpret_cast<const float4*>(xb + (size_t)gg * NC + c4);
            vv[k][0] = v.x; vv[k][1] = v.y; vv[k][2] = v.z; vv[k][3] = v.w;
        }
        #pragma unroll
        for (int j = 0; j < 4; ++j) {
            const int kc = (j + l) & 3;
            const unsigned int lo = (unsigned int)f2b(vv[0][kc]) | ((unsigned int)f2b(vv[1][kc]) << 16);
            const unsigned int hi = (unsigned int)f2b(vv[2][kc]) | ((unsigned int)f2b(vv[3][kc]) << 16);
            uint2 pw = {lo, hi};
            *reinterpret_cast<uint2*>(&sxT[(c4 + kc) * SXT_LD + 4 * p4]) = pw;
        }
    }
    __syncthreads();

    const int lane = tid & 63, w = tid >> 6;
    const int i16 = lane & 15, g = lane >> 4;
    const int i0 = 16 * w + 4 * g;

    const int fbase[NS] = {0, 2, 4, 6, 9};
    const int ksn[NS]   = {2, 2, 2, 3, 4};
    const int RA[NS]    = {16, 16, 24, 40, 56};

    #pragma unroll
    for (int ct = 0; ct < 4; ++ct) {
        const int c = 16 * ct + i16;

        // ---- causal-stat inputs: 19 coalesced global dwords (L1/L2-hot) ----
        float f[19];
        #pragma unroll
        for (int q = 0; q < 19; ++q) {
            int gg = t0 + i0 - 15 + q;
            if (gg < 0) gg = 0;                 // replicate-left pad
            f[q] = xb[(size_t)gg * NC + c];
        }
        float s1 = 0.f, s2 = 0.f;
        #pragma unroll
        for (int q = 0; q < 16; ++q) { const float v = f[q]; s1 += v; s2 = fmaf(v, v, s2); }
        float zf[4], lvf[4];
        #pragma unroll
        for (int d = 0; d < 4; ++d) {
            const int tglob = t0 + i0 + d;
            const float eff = fminf((float)(tglob + 1), 16.0f);
            const float re = __fdividef(1.0f, eff + 1e-12f);
            const float mn = s1 * re;
            const float m2 = s2 * re;
            const float var = fmaxf(m2 - mn * mn, 0.f);
            zf[d]  = (f[15 + d] - mn) * rsqrtf(var + 1e-6f);
            lvf[d] = __logf(var + 1e-6f);
            if (d < 3) {
                const float ad = f[16 + d], sb = f[d];
                s1 += ad - sb;
                s2 += ad * ad - sb * sb;
            }
        }

        // ---- issue all table gathers early (adjacent 16B pair per d) ----
        uint4 r0[4], r1[4];
        float azr[4], avr[4];
        bool fastp[4];
        #pragma unroll
        for (int d = 0; d < 4; ++d) {
            const int tglob = t0 + i0 + d;
            // t>=15 guarantees |z| <= 15/sqrt(16) = 3.75; lv >= log(1e-6) always
            fastp[d] = (!SLOW) && (tglob >= 15) && (fabsf(zf[d]) <= 3.9f) && (lvf[d] <= 3.9f);
            float fz = (zf[d] - ZMINF) * ZSCLF;
            float fv = (lvf[d] - VMINF) * VSCLF;
            fz = fminf(fmaxf(fz, 0.f), 510.0f);
            fv = fminf(fmaxf(fv, 0.f), 254.0f);
            const int zi = (int)fz, vi = (int)fv;
            azr[d] = fz - (float)zi;
            avr[d] = fv - (float)vi;
            const int cidx = vi * NZ + zi;       // [vi][zi] layout
            if (!SLOW) {
                r0[d] = tb4[cidx];               // corners (zi, vi/vi+1)
                r1[d] = tb4[cidx + 1];           // corners (zi+1, vi/vi+1) -- adjacent
            }
        }

        // ---- conv via MFMA: 13 k-steps over 5 sigmas ----
        f32x4 acc[NS];
        #pragma unroll
        for (int s = 0; s < NS; ++s) acc[s] = (f32x4){0.f, 0.f, 0.f, 0.f};
        #pragma unroll
        for (int s = 0; s < NS; ++s) {
            #pragma unroll
            for (int kk = 0; kk < ksn[s]; ++kk) {
                const bf16x8 A = *reinterpret_cast<const bf16x8*>(&afr4[(fbase[s] + kk) * 64 + lane]);
                const int tof = 16 * w - RA[s] + 32 * kk + RMX + 8 * g;
                const bf16x8 B = *reinterpret_cast<const bf16x8*>(&sxT[c * SXT_LD + tof]);
                acc[s] = __builtin_amdgcn_mfma_f32_16x16x32_bf16(A, B, acc[s], 0, 0, 0);
            }
        }

        // ---- consume: bilerp, blend, store (rare inline fast-erf fallback) ----
        #pragma unroll
        for (int d = 0; d < 4; ++d) {
            const int tglob = t0 + i0 + d;
            const float y0 = acc[0][d], y1 = acc[1][d], y2 = acc[2][d],
                        y3 = acc[3][d], y4 = acc[4][d];
            float res;
            if (fastp[d]) {
                const float av = avr[d], az = azr[d];
                const uint4 q0 = r0[d], q1 = r1[d];
                const float c00 = fmaf(av, hlo(q0.z) - hlo(q0.x), hlo(q0.x));
                const float c01 = fmaf(av, hhi(q0.z) - hhi(q0.x), hhi(q0.x));
                const float c02 = fmaf(av, hlo(q0.w) - hlo(q0.y), hlo(q0.y));
                const float c03 = fmaf(av, hhi(q0.w) - hhi(q0.y), hhi(q0.y));
                const float c10 = fmaf(av, hlo(q1.z) - hlo(q1.x), hlo(q1.x));
                const float c11 = fmaf(av, hhi(q1.z) - hhi(q1.x), hhi(q1.x));
                const float c12 = fmaf(av, hlo(q1.w) - hlo(q1.y), hlo(q1.y));
                const float c13 = fmaf(av, hhi(q1.w) - hhi(q1.y), hhi(q1.y));
                const float w0 = fmaf(az, c10 - c00, c00);
                const float w1 = fmaf(az, c11 - c01, c01);
                const float w2 = fmaf(az, c12 - c02, c02);
                const float w3 = fmaf(az, c13 - c03, c03);
                res = y4;
                res = fmaf(w0, y0 - y4, res);
                res = fmaf(w1, y1 - y4, res);
                res = fmaf(w2, y2 - y4, res);
                res = fmaf(w3, y3 - y4, res);
            } else {
                float wv[5];
                mlp_w_fast(zf[d], lvf[d], W1, b1, W2, b2, wv);
                res = wv[0] * y0;
                res = fmaf(wv[1], y1, res);
                res = fmaf(wv[2], y2, res);
                res = fmaf(wv[3], y3, res);
                res = fmaf(wv[4], y4, res);
            }
            out[((size_t)b * NT + tglob) * NC + c] = res;
        }
    }
}

extern "C" void kernel_launch(void* const* d_in, const int* in_sizes, int n_in,
                              void* d_out, int out_size, void* d_ws, size_t ws_size,
                              hipStream_t stream) {
    const float* x  = (const float*)d_in[0];
    const float* W1 = (const float*)d_in[1];
    const float* b1 = (const float*)d_in[2];
    const float* W2 = (const float*)d_in[3];
    const float* b2 = (const float*)d_in[4];
    float* out = (float*)d_out;
    unsigned short* afr = (unsigned short*)d_ws;              // 13312 B used
    unsigned int* tbl = (unsigned int*)((char*)d_ws + FRAG_BYTES);
    const int build_tbl = (ws_size >= WS_NEED) ? 1 : 0;

    init_all_kernel<<<1 + (NZ * NV) / 256, 256, 0, stream>>>(W1, b1, W2, b2, afr, tbl, build_tbl);
    if (build_tbl) {
        fused6_kernel<false><<<NB * (NT / TTILE), 256, 0, stream>>>(
            x, W1, b1, W2, b2, (const uint4*)afr, (const uint4*)tbl, out);
    } else {
        fused6_kernel<true><<<NB * (NT / TTILE), 256, 0, stream>>>(
            x, W1, b1, W2, b2, (const uint4*)afr, (const uint4*)tbl, out);
    }
}

// Round 7
// 97.525 us; speedup vs baseline: 1.0533x; 1.0533x over previous
//
#include <hip/hip_runtime.h>
#include <math.h>

// Problem constants (fixed by setup_inputs)
#define NB 16
#define NT 4096
#define NC 64
#define NS 5
#define NH 32

#define TTILE 64
#define RMX 56
#define PN (TTILE + 2*RMX)   // 176 staged t-positions per tile

// tap table segment offsets: radii {10,16,24,36,56} -> lengths {21,33,49,73,113}
#define OFF0 0
#define OFF1 21
#define OFF2 54
#define OFF3 103
#define OFF4 176
#define NTAPS 289

#define NFRAG 13            // K-steps total: 2+2+2+3+4
#define SXT_LD 184          // bf16 elements per channel row
#define SXS_LD 20           // f32 stride for stats rows (16B-aligned, bank-spread)
#define SXS_ROWS 79         // rows t0-15 .. t0+63

// MLP weight-table (z, logvar) -> 4 softmax weights (5th = 1 - sum)
// layout: [vi][zi], cell = 16B {w0..3 fp16 @ (zi,vi) | w0..3 fp16 @ (zi,vi+1)}
#define NZ 512
#define NV 256
#define ZMINF (-4.0f)
#define VMINF (-14.0f)
#define ZSCLF (511.0f / 8.0f)
#define VSCLF (255.0f / 18.0f)
#define FRAG_BYTES 16384
#define TABLE_BYTES ((size_t)NZ * NV * 16)
#define WS_NEED (FRAG_BYTES + TABLE_BYTES)

typedef __attribute__((ext_vector_type(8))) short bf16x8;
typedef __attribute__((ext_vector_type(4))) float f32x4;

__device__ __forceinline__ unsigned short f2b(float f) {
    unsigned int u = __float_as_uint(f);
    unsigned int r = (u + 0x7fffu + ((u >> 16) & 1u)) >> 16;   // RNE
    return (unsigned short)r;
}
__device__ __forceinline__ float hlo(unsigned int u) {
    union { unsigned int u_; _Float16 h[2]; } t; t.u_ = u; return (float)t.h[0];
}
__device__ __forceinline__ float hhi(unsigned int u) {
    union { unsigned int u_; _Float16 h[2]; } t; t.u_ = u; return (float)t.h[1];
}
__device__ __forceinline__ unsigned int packh2(float a, float b) {
    union { unsigned int u_; _Float16 h[2]; } t;
    t.h[0] = (_Float16)a; t.h[1] = (_Float16)b; return t.u_;
}

// Abramowitz-Stegun 7.1.26, |err| <= 1.5e-7, branchless, no libm.
__device__ __forceinline__ float fast_erf(float x) {
    const float ax = fabsf(x);
    const float t = __fdividef(1.0f, fmaf(0.3275911f, ax, 1.0f));
    float p = fmaf(t, 1.061405429f, -1.453152027f);
    p = fmaf(t, p, 1.421413741f);
    p = fmaf(t, p, -0.284496736f);
    p = fmaf(t, p, 0.254829592f);
    p *= t;
    const float e = __expf(-ax * ax);
    const float r = fmaf(-p, e, 1.0f);
    return copysignf(r, x);
}

// exact-MLP softmax weights (fast-erf flavor): table build + rare slow path
__device__ __forceinline__ void mlp_w_fast(
    float z, float lv,
    const float* __restrict__ W1, const float* __restrict__ b1,
    const float* __restrict__ W2, const float* __restrict__ b2,
    float* __restrict__ wout)
{
    float l0 = b2[0], l1 = b2[1], l2 = b2[2], l3 = b2[3], l4 = b2[4];
    #pragma unroll 4
    for (int j = 0; j < NH; ++j) {
        const float a = fmaf(z, W1[2 * j], fmaf(lv, W1[2 * j + 1], b1[j]));
        const float g = 0.5f * a * (1.0f + fast_erf(a * 0.70710678118654752f));
        l0 = fmaf(g, W2[j],          l0);
        l1 = fmaf(g, W2[NH + j],     l1);
        l2 = fmaf(g, W2[2 * NH + j], l2);
        l3 = fmaf(g, W2[3 * NH + j], l3);
        l4 = fmaf(g, W2[4 * NH + j], l4);
    }
    const float sc = 1.4285714285714286f;
    const float mx = fmaxf(fmaxf(fmaxf(l0, l1), fmaxf(l2, l3)), l4);
    const float e0 = __expf((l0 - mx) * sc);
    const float e1 = __expf((l1 - mx) * sc);
    const float e2 = __expf((l2 - mx) * sc);
    const float e3 = __expf((l3 - mx) * sc);
    const float e4 = __expf((l4 - mx) * sc);
    const float rd = __fdividef(1.0f, e0 + e1 + e2 + e3 + e4);
    wout[0] = e0 * rd; wout[1] = e1 * rd; wout[2] = e2 * rd;
    wout[3] = e3 * rd; wout[4] = e4 * rd;
}

// ---------------- single init launch: block 0 -> A-frags; blocks 1.. -> LUT ----------------
__global__ void init_all_kernel(
    const float* __restrict__ W1, const float* __restrict__ b1,
    const float* __restrict__ W2, const float* __restrict__ b2,
    unsigned short* __restrict__ afr, unsigned int* __restrict__ tbl, int build_tbl)
{
    const int tid = threadIdx.x;
    if (blockIdx.x == 0) {
        __shared__ float raw[NTAPS];
        __shared__ float invs[NS];
        const int offs[6] = {OFF0, OFF1, OFF2, OFF3, OFF4, NTAPS};
        const float sig[NS] = {2.5f, 4.0f, 6.0f, 9.0f, 14.0f};
        const int RR[NS] = {10, 16, 24, 36, 56};
        for (int i = tid; i < NTAPS; i += blockDim.x) {
            int s = 0;
            #pragma unroll
            for (int k = 1; k < NS; ++k) if (i >= offs[k]) s = k;
            const int j = i - offs[s] - RR[s];
            const float u = (float)j / sig[s];
            raw[i] = __expf(-0.5f * u * u);
        }
        __syncthreads();
        if (tid < NS) {
            float sum = 0.f;
            for (int i = offs[tid]; i < offs[tid + 1]; ++i) sum += raw[i];
            invs[tid] = 1.0f / (sum + 1e-12f);
        }
        __syncthreads();
        const int fbase6[6] = {0, 2, 4, 6, 9, 13};
        const int RA[NS] = {16, 16, 24, 40, 56};
        for (int idx = tid; idx < NFRAG * 64 * 8; idx += blockDim.x) {
            const int f = idx >> 9;
            const int lane = (idx >> 3) & 63;
            const int e = idx & 7;
            int s = 0;
            #pragma unroll
            for (int k = 1; k < NS; ++k) if (f >= fbase6[k]) s = k;
            const int kk = f - fbase6[s];
            const int r = lane & 15;
            const int g = lane >> 4;
            const int j = 32 * kk + 8 * g + e - RA[s] - r;
            float v = 0.f;
            if (j >= -RR[s] && j <= RR[s]) v = raw[offs[s] + j + RR[s]] * invs[s];
            afr[idx] = f2b(v);
        }
    } else if (build_tbl) {
        const int idx = (blockIdx.x - 1) * 256 + tid;   // zi*NV + vi (compute grid)
        const int zi = idx / NV, vi = idx % NV;
        const float z  = ZMINF + (float)zi * (8.0f / 511.0f);
        const float lv = VMINF + (float)vi * (18.0f / 255.0f);
        float w[5];
        mlp_w_fast(z, lv, W1, b1, W2, b2, w);
        const unsigned int p01 = packh2(w[0], w[1]);
        const unsigned int p23 = packh2(w[2], w[3]);
        uint2 p = {p01, p23};
        // storage layout [vi][zi]: cell c(vi,zi) = {w @ (zi,vi) | w @ (zi,vi+1)}
        *reinterpret_cast<uint2*>(tbl + ((size_t)vi * NZ + zi) * 4) = p;          // own lo
        if (vi > 0)
            *reinterpret_cast<uint2*>(tbl + ((size_t)(vi - 1) * NZ + zi) * 4 + 2) = p; // row below's hi
        if (vi == NV - 1)
            *reinterpret_cast<uint2*>(tbl + ((size_t)vi * NZ + zi) * 4 + 2) = p;       // self hi (clamp)
    }
}

// ---------------- fused main kernel ----------------
// grid: 4 cq-planes x (NB * NT/TTILE) blocks; block = (cq, b, 64-t tile).
// Each block covers 64 t x 16 c; wave wv covers t rows [16wv,16wv+16) x 16 c.
// One 16x16 MFMA tile set per wave -- no ct loop, short latency chains.
template<bool SLOW>
__global__ __launch_bounds__(256, 8) void fused7_kernel(
    const float* __restrict__ x,  const float* __restrict__ W1,
    const float* __restrict__ b1, const float* __restrict__ W2,
    const float* __restrict__ b2, const uint4* __restrict__ afr4,
    const uint4* __restrict__ tb4, float* __restrict__ out)
{
    __shared__ __align__(16) short sxT[16 * SXT_LD];          // bf16 [c][t], 5888 B
    __shared__ __align__(16) float sxS[SXS_ROWS * SXS_LD];    // f32  [t][c], 6320 B

    const int blk = blockIdx.x;
    const int bt = blk & 1023;
    const int cq = blk >> 10;             // slowest dim: same-XCD residue for all cq of a (b,t) tile
    const int b  = bt >> 6;
    const int t0 = (bt & 63) * TTILE;
    const int c0 = cq << 4;
    const float* xb = x + (size_t)b * NT * NC;
    const int tid = threadIdx.x;

    // ---- stage sxT (bf16 [c][t], reflect-padded): 44 p4-groups x 4 c4-groups ----
    if (tid < 44 * 4) {
        const int p4 = tid >> 2;
        const int l  = tid & 3;
        const int c4 = l << 2;
        float vv[4][4];
        #pragma unroll
        for (int k = 0; k < 4; ++k) {
            int gg = t0 - RMX + 4 * p4 + k;
            if (gg < 0) gg = -gg;
            if (gg >= NT) gg = 2 * NT - 2 - gg;
            const float4 v = *reinterpret_cast<const float4*>(xb + (size_t)gg * NC + c0 + c4);
            vv[k][0] = v.x; vv[k][1] = v.y; vv[k][2] = v.z; vv[k][3] = v.w;
        }
        #pragma unroll
        for (int j = 0; j < 4; ++j) {
            const int kc = (j + l) & 3;
            const unsigned int lo = (unsigned int)f2b(vv[0][kc]) | ((unsigned int)f2b(vv[1][kc]) << 16);
            const unsigned int hi = (unsigned int)f2b(vv[2][kc]) | ((unsigned int)f2b(vv[3][kc]) << 16);
            uint2 pw = {lo, hi};
            *reinterpret_cast<uint2*>(&sxT[(c4 + kc) * SXT_LD + 4 * p4]) = pw;
        }
    }
    // ---- stage sxS (f32 [t][c], replicate-left): 79 rows x 4 c4-groups ----
    for (int idx = tid; idx < SXS_ROWS * 4; idx += 256) {
        const int p = idx >> 2, c4 = (idx & 3) << 2;
        int gg = t0 - 15 + p; if (gg < 0) gg = 0;
        const float4 v = *reinterpret_cast<const float4*>(xb + (size_t)gg * NC + c0 + c4);
        *reinterpret_cast<float4*>(&sxS[p * SXS_LD + c4]) = v;
    }
    __syncthreads();

    const int lane = tid & 63, wv = tid >> 6;
    const int i16 = lane & 15, g = lane >> 4;
    const int i0 = 16 * wv + 4 * g;
    const int c = c0 + i16;

    const int fbase[NS] = {0, 2, 4, 6, 9};
    const int ksn[NS]   = {2, 2, 2, 3, 4};
    const int RA[NS]    = {16, 16, 24, 40, 56};

    // ---- causal stats: 19 LDS dwords ----
    float f[19];
    #pragma unroll
    for (int q = 0; q < 19; ++q) f[q] = sxS[(i0 + q) * SXS_LD + i16];
    float s1 = 0.f, s2 = 0.f;
    #pragma unroll
    for (int q = 0; q < 16; ++q) { const float v = f[q]; s1 += v; s2 = fmaf(v, v, s2); }
    float zf[4], lvf[4];
    #pragma unroll
    for (int d = 0; d < 4; ++d) {
        const int tglob = t0 + i0 + d;
        const float eff = fminf((float)(tglob + 1), 16.0f);
        const float re = __fdividef(1.0f, eff + 1e-12f);
        const float mn = s1 * re;
        const float m2 = s2 * re;
        const float var = fmaxf(m2 - mn * mn, 0.f);
        zf[d]  = (f[15 + d] - mn) * rsqrtf(var + 1e-6f);
        lvf[d] = __logf(var + 1e-6f);
        if (d < 3) {
            const float ad = f[16 + d], sb = f[d];
            s1 += ad - sb;
            s2 += ad * ad - sb * sb;
        }
    }

    // ---- issue all table gathers (adjacent 16B pair per d), batched ----
    uint4 r0[4], r1[4];
    float azr[4], avr[4];
    bool fastp[4];
    #pragma unroll
    for (int d = 0; d < 4; ++d) {
        const int tglob = t0 + i0 + d;
        // t>=15 guarantees |z| <= 15/sqrt(16) = 3.75; lv >= log(1e-6) always
        fastp[d] = (!SLOW) && (tglob >= 15) && (fabsf(zf[d]) <= 3.9f) && (lvf[d] <= 3.9f);
        float fz = (zf[d] - ZMINF) * ZSCLF;
        float fv = (lvf[d] - VMINF) * VSCLF;
        fz = fminf(fmaxf(fz, 0.f), 510.0f);
        fv = fminf(fmaxf(fv, 0.f), 254.0f);
        const int zi = (int)fz, vi = (int)fv;
        azr[d] = fz - (float)zi;
        avr[d] = fv - (float)vi;
        const int cidx = vi * NZ + zi;       // [vi][zi] layout
        if (!SLOW) {
            r0[d] = tb4[cidx];               // corners (zi, vi/vi+1)
            r1[d] = tb4[cidx + 1];           // corners (zi+1, vi/vi+1) -- adjacent
        }
    }

    // ---- conv via MFMA: 13 k-steps over 5 sigmas ----
    f32x4 acc[NS];
    #pragma unroll
    for (int s = 0; s < NS; ++s) acc[s] = (f32x4){0.f, 0.f, 0.f, 0.f};
    #pragma unroll
    for (int s = 0; s < NS; ++s) {
        #pragma unroll
        for (int kk = 0; kk < ksn[s]; ++kk) {
            const bf16x8 A = *reinterpret_cast<const bf16x8*>(&afr4[(fbase[s] + kk) * 64 + lane]);
            const int tof = 16 * wv - RA[s] + 32 * kk + RMX + 8 * g;
            const bf16x8 B = *reinterpret_cast<const bf16x8*>(&sxT[i16 * SXT_LD + tof]);
            acc[s] = __builtin_amdgcn_mfma_f32_16x16x32_bf16(A, B, acc[s], 0, 0, 0);
        }
    }

    // ---- consume: bilerp, blend, store (rare inline fast-erf fallback) ----
    #pragma unroll
    for (int d = 0; d < 4; ++d) {
        const int tglob = t0 + i0 + d;
        const float y0 = acc[0][d], y1 = acc[1][d], y2 = acc[2][d],
                    y3 = acc[3][d], y4 = acc[4][d];
        float res;
        if (fastp[d]) {
            const float av = avr[d], az = azr[d];
            const uint4 q0 = r0[d], q1 = r1[d];
            const float c00 = fmaf(av, hlo(q0.z) - hlo(q0.x), hlo(q0.x));
            const float c01 = fmaf(av, hhi(q0.z) - hhi(q0.x), hhi(q0.x));
            const float c02 = fmaf(av, hlo(q0.w) - hlo(q0.y), hlo(q0.y));
            const float c03 = fmaf(av, hhi(q0.w) - hhi(q0.y), hhi(q0.y));
            const float c10 = fmaf(av, hlo(q1.z) - hlo(q1.x), hlo(q1.x));
            const float c11 = fmaf(av, hhi(q1.z) - hhi(q1.x), hhi(q1.x));
            const float c12 = fmaf(av, hlo(q1.w) - hlo(q1.y), hlo(q1.y));
            const float c13 = fmaf(av, hhi(q1.w) - hhi(q1.y), hhi(q1.y));
            const float w0 = fmaf(az, c10 - c00, c00);
            const float w1 = fmaf(az, c11 - c01, c01);
            const float w2 = fmaf(az, c12 - c02, c02);
            const float w3 = fmaf(az, c13 - c03, c03);
            res = y4;
            res = fmaf(w0, y0 - y4, res);
            res = fmaf(w1, y1 - y4, res);
            res = fmaf(w2, y2 - y4, res);
            res = fmaf(w3, y3 - y4, res);
        } else {
            float wv5[5];
            mlp_w_fast(zf[d], lvf[d], W1, b1, W2, b2, wv5);
            res = wv5[0] * y0;
            res = fmaf(wv5[1], y1, res);
            res = fmaf(wv5[2], y2, res);
            res = fmaf(wv5[3], y3, res);
            res = fmaf(wv5[4], y4, res);
        }
        out[((size_t)b * NT + tglob) * NC + c] = res;
    }
}

extern "C" void kernel_launch(void* const* d_in, const int* in_sizes, int n_in,
                              void* d_out, int out_size, void* d_ws, size_t ws_size,
                              hipStream_t stream) {
    const float* x  = (const float*)d_in[0];
    const float* W1 = (const float*)d_in[1];
    const float* b1 = (const float*)d_in[2];
    const float* W2 = (const float*)d_in[3];
    const float* b2 = (const float*)d_in[4];
    float* out = (float*)d_out;
    unsigned short* afr = (unsigned short*)d_ws;              // 13312 B used
    unsigned int* tbl = (unsigned int*)((char*)d_ws + FRAG_BYTES);
    const int build_tbl = (ws_size >= WS_NEED) ? 1 : 0;

    init_all_kernel<<<1 + (NZ * NV) / 256, 256, 0, stream>>>(W1, b1, W2, b2, afr, tbl, build_tbl);
    if (build_tbl) {
        fused7_kernel<false><<<4 * NB * (NT / TTILE), 256, 0, stream>>>(
            x, W1, b1, W2, b2, (const uint4*)afr, (const uint4*)tbl, out);
    } else {
        fused7_kernel<true><<<4 * NB * (NT / TTILE), 256, 0, stream>>>(
            x, W1, b1, W2, b2, (const uint4*)afr, (const uint4*)tbl, out);
    }
}

// Round 8
// 69.445 us; speedup vs baseline: 1.4792x; 1.4044x over previous
//
#include <hip/hip_runtime.h>
#include <math.h>

// Problem constants (fixed by setup_inputs)
#define NB 16
#define NT 4096
#define NC 64
#define NS 5
#define NH 32

#define TTILE 64
#define RMX 56
#define PN (TTILE + 2*RMX)   // 176 staged t-positions per tile

// tap table segment offsets: radii {10,16,24,36,56} -> lengths {21,33,49,73,113}
#define OFF0 0
#define OFF1 21
#define OFF2 54
#define OFF3 103
#define OFF4 176
#define NTAPS 289

#define NFRAG 13            // K-steps total: 2+2+2+3+4
#define SXT_LD 184          // bf16 elements per channel row
#define SXS_LD 20           // f32 stride for stats rows
#define SXS_ROWS 79         // rows t0-15 .. t0+63

// MLP weight-table (z, logvar) -> 4 softmax weights (5th = 1 - sum)
// layout: [vi][zi], cell = 16B {w0..3 fp16 @ (zi,vi) | w0..3 fp16 @ (zi,vi+1)}
#define NZ 512
#define NV 256
#define ZMINF (-4.0f)
#define VMINF (-14.0f)
#define ZSCLF (511.0f / 8.0f)
#define VSCLF (255.0f / 18.0f)
#define FRAG_BYTES 16384
#define TABLE_BYTES ((size_t)NZ * NV * 16)
#define WS_NEED (FRAG_BYTES + TABLE_BYTES)

typedef __attribute__((ext_vector_type(8))) short bf16x8;
typedef __attribute__((ext_vector_type(4))) float f32x4;

__device__ __forceinline__ unsigned short f2b(float f) {
    unsigned int u = __float_as_uint(f);
    unsigned int r = (u + 0x7fffu + ((u >> 16) & 1u)) >> 16;   // RNE
    return (unsigned short)r;
}
__device__ __forceinline__ float hlo(unsigned int u) {
    union { unsigned int u_; _Float16 h[2]; } t; t.u_ = u; return (float)t.h[0];
}
__device__ __forceinline__ float hhi(unsigned int u) {
    union { unsigned int u_; _Float16 h[2]; } t; t.u_ = u; return (float)t.h[1];
}
__device__ __forceinline__ unsigned int packh2(float a, float b) {
    union { unsigned int u_; _Float16 h[2]; } t;
    t.h[0] = (_Float16)a; t.h[1] = (_Float16)b; return t.u_;
}

// Abramowitz-Stegun 7.1.26, |err| <= 1.5e-7, branchless, no libm.
__device__ __forceinline__ float fast_erf(float x) {
    const float ax = fabsf(x);
    const float t = __fdividef(1.0f, fmaf(0.3275911f, ax, 1.0f));
    float p = fmaf(t, 1.061405429f, -1.453152027f);
    p = fmaf(t, p, 1.421413741f);
    p = fmaf(t, p, -0.284496736f);
    p = fmaf(t, p, 0.254829592f);
    p *= t;
    const float e = __expf(-ax * ax);
    const float r = fmaf(-p, e, 1.0f);
    return copysignf(r, x);
}

// exact-MLP softmax weights (fast-erf flavor): table build + rare slow path
__device__ __forceinline__ void mlp_w_fast(
    float z, float lv,
    const float* __restrict__ W1, const float* __restrict__ b1,
    const float* __restrict__ W2, const float* __restrict__ b2,
    float* __restrict__ wout)
{
    float l0 = b2[0], l1 = b2[1], l2 = b2[2], l3 = b2[3], l4 = b2[4];
    #pragma unroll 4
    for (int j = 0; j < NH; ++j) {
        const float a = fmaf(z, W1[2 * j], fmaf(lv, W1[2 * j + 1], b1[j]));
        const float g = 0.5f * a * (1.0f + fast_erf(a * 0.70710678118654752f));
        l0 = fmaf(g, W2[j],          l0);
        l1 = fmaf(g, W2[NH + j],     l1);
        l2 = fmaf(g, W2[2 * NH + j], l2);
        l3 = fmaf(g, W2[3 * NH + j], l3);
        l4 = fmaf(g, W2[4 * NH + j], l4);
    }
    const float sc = 1.4285714285714286f;
    const float mx = fmaxf(fmaxf(fmaxf(l0, l1), fmaxf(l2, l3)), l4);
    const float e0 = __expf((l0 - mx) * sc);
    const float e1 = __expf((l1 - mx) * sc);
    const float e2 = __expf((l2 - mx) * sc);
    const float e3 = __expf((l3 - mx) * sc);
    const float e4 = __expf((l4 - mx) * sc);
    const float rd = __fdividef(1.0f, e0 + e1 + e2 + e3 + e4);
    wout[0] = e0 * rd; wout[1] = e1 * rd; wout[2] = e2 * rd;
    wout[3] = e3 * rd; wout[4] = e4 * rd;
}

// ---------------- single init launch: block 0 -> A-frags; blocks 1.. -> LUT ----------------
__global__ void init_all_kernel(
    const float* __restrict__ W1, const float* __restrict__ b1,
    const float* __restrict__ W2, const float* __restrict__ b2,
    unsigned short* __restrict__ afr, unsigned int* __restrict__ tbl, int build_tbl)
{
    const int tid = threadIdx.x;
    if (blockIdx.x == 0) {
        __shared__ float raw[NTAPS];
        __shared__ float invs[NS];
        const int offs[6] = {OFF0, OFF1, OFF2, OFF3, OFF4, NTAPS};
        const float sig[NS] = {2.5f, 4.0f, 6.0f, 9.0f, 14.0f};
        const int RR[NS] = {10, 16, 24, 36, 56};
        for (int i = tid; i < NTAPS; i += blockDim.x) {
            int s = 0;
            #pragma unroll
            for (int k = 1; k < NS; ++k) if (i >= offs[k]) s = k;
            const int j = i - offs[s] - RR[s];
            const float u = (float)j / sig[s];
            raw[i] = __expf(-0.5f * u * u);
        }
        __syncthreads();
        if (tid < NS) {
            float sum = 0.f;
            for (int i = offs[tid]; i < offs[tid + 1]; ++i) sum += raw[i];
            invs[tid] = 1.0f / (sum + 1e-12f);
        }
        __syncthreads();
        const int fbase6[6] = {0, 2, 4, 6, 9, 13};
        const int RA[NS] = {16, 16, 24, 40, 56};
        for (int idx = tid; idx < NFRAG * 64 * 8; idx += blockDim.x) {
            const int f = idx >> 9;
            const int lane = (idx >> 3) & 63;
            const int e = idx & 7;
            int s = 0;
            #pragma unroll
            for (int k = 1; k < NS; ++k) if (f >= fbase6[k]) s = k;
            const int kk = f - fbase6[s];
            const int r = lane & 15;
            const int g = lane >> 4;
            const int j = 32 * kk + 8 * g + e - RA[s] - r;
            float v = 0.f;
            if (j >= -RR[s] && j <= RR[s]) v = raw[offs[s] + j + RR[s]] * invs[s];
            afr[idx] = f2b(v);
        }
    } else if (build_tbl) {
        const int idx = (blockIdx.x - 1) * 256 + tid;   // zi*NV + vi (compute grid)
        const int zi = idx / NV, vi = idx % NV;
        const float z  = ZMINF + (float)zi * (8.0f / 511.0f);
        const float lv = VMINF + (float)vi * (18.0f / 255.0f);
        float w[5];
        mlp_w_fast(z, lv, W1, b1, W2, b2, w);
        const unsigned int p01 = packh2(w[0], w[1]);
        const unsigned int p23 = packh2(w[2], w[3]);
        uint2 p = {p01, p23};
        // storage layout [vi][zi]: cell c(vi,zi) = {w @ (zi,vi) | w @ (zi,vi+1)}
        *reinterpret_cast<uint2*>(tbl + ((size_t)vi * NZ + zi) * 4) = p;          // own lo
        if (vi > 0)
            *reinterpret_cast<uint2*>(tbl + ((size_t)(vi - 1) * NZ + zi) * 4 + 2) = p; // row below's hi
        if (vi == NV - 1)
            *reinterpret_cast<uint2*>(tbl + ((size_t)vi * NZ + zi) * 4 + 2) = p;       // self hi (clamp)
    }
}

// ---------------- fused main kernel ----------------
// grid: 4 cq-planes x (NB * NT/TTILE); block = (cq, b, 64-t tile) = 64 t x 16 c.
// Wave wv: t rows [16wv,16wv+16) x 16 c. Register phases kept disjoint:
// stats -> (gathers+bilerp -> 16 weights) -> MFMA(20 acc) -> blend/store.
template<bool SLOW>
__global__ __launch_bounds__(256, 8) void fused8_kernel(
    const float* __restrict__ x,  const float* __restrict__ W1,
    const float* __restrict__ b1, const float* __restrict__ W2,
    const float* __restrict__ b2, const uint4* __restrict__ afr4,
    const uint4* __restrict__ tb4, float* __restrict__ out)
{
    __shared__ __align__(16) short sxT[16 * SXT_LD];          // bf16 [c][t], 5888 B
    __shared__ __align__(16) float sxS[SXS_ROWS * SXS_LD];    // f32  [t][c], 6320 B

    const int blk = blockIdx.x;
    const int bt = blk & 1023;
    const int cq = blk >> 10;             // slowest dim
    const int b  = bt >> 6;
    const int t0 = (bt & 63) * TTILE;
    const int c0 = cq << 4;
    const float* xb = x + (size_t)b * NT * NC;
    const int tid = threadIdx.x;

    // ---- stage sxT (bf16 [c][t], reflect-padded): 44 p4-groups x 4 c4-groups ----
    if (tid < 44 * 4) {
        const int p4 = tid >> 2;
        const int l  = tid & 3;
        const int c4 = l << 2;
        float vv[4][4];
        #pragma unroll
        for (int k = 0; k < 4; ++k) {
            int gg = t0 - RMX + 4 * p4 + k;
            if (gg < 0) gg = -gg;
            if (gg >= NT) gg = 2 * NT - 2 - gg;
            const float4 v = *reinterpret_cast<const float4*>(xb + (size_t)gg * NC + c0 + c4);
            vv[k][0] = v.x; vv[k][1] = v.y; vv[k][2] = v.z; vv[k][3] = v.w;
        }
        #pragma unroll
        for (int j = 0; j < 4; ++j) {
            const int kc = (j + l) & 3;
            const unsigned int lo = (unsigned int)f2b(vv[0][kc]) | ((unsigned int)f2b(vv[1][kc]) << 16);
            const unsigned int hi = (unsigned int)f2b(vv[2][kc]) | ((unsigned int)f2b(vv[3][kc]) << 16);
            uint2 pw = {lo, hi};
            *reinterpret_cast<uint2*>(&sxT[(c4 + kc) * SXT_LD + 4 * p4]) = pw;
        }
    }
    // ---- stage sxS (f32 [t][c], replicate-left): 79 rows x 4 c4-groups ----
    for (int idx = tid; idx < SXS_ROWS * 4; idx += 256) {
        const int p = idx >> 2, c4 = (idx & 3) << 2;
        int gg = t0 - 15 + p; if (gg < 0) gg = 0;
        const float4 v = *reinterpret_cast<const float4*>(xb + (size_t)gg * NC + c0 + c4);
        *reinterpret_cast<float4*>(&sxS[p * SXS_LD + c4]) = v;
    }
    __syncthreads();

    const int lane = tid & 63, wv = tid >> 6;
    const int i16 = lane & 15, g = lane >> 4;
    const int i0 = 16 * wv + 4 * g;

    // ---- causal stats: 19 LDS dwords -> zf, lvf ----
    float zf[4], lvf[4];
    {
        float f[19];
        #pragma unroll
        for (int q = 0; q < 19; ++q) f[q] = sxS[(i0 + q) * SXS_LD + i16];
        float s1 = 0.f, s2 = 0.f;
        #pragma unroll
        for (int q = 0; q < 16; ++q) { const float v = f[q]; s1 += v; s2 = fmaf(v, v, s2); }
        #pragma unroll
        for (int d = 0; d < 4; ++d) {
            const int tglob = t0 + i0 + d;
            const float eff = fminf((float)(tglob + 1), 16.0f);
            const float re = __fdividef(1.0f, eff + 1e-12f);
            const float mn = s1 * re;
            const float m2 = s2 * re;
            const float var = fmaxf(m2 - mn * mn, 0.f);
            zf[d]  = (f[15 + d] - mn) * rsqrtf(var + 1e-6f);
            lvf[d] = __logf(var + 1e-6f);
            if (d < 3) {
                const float ad = f[16 + d], sb = f[d];
                s1 += ad - sb;
                s2 += ad * ad - sb * sb;
            }
        }
    }

    // ---- resolve all 16 blend weights BEFORE the conv (two half-batches) ----
    float wg0[4], wg1[4], wg2[4], wg3[4];
    #pragma unroll
    for (int h = 0; h < 2; ++h) {
        uint4 q0[2], q1[2];
        float az[2], av[2];
        bool fp[2];
        #pragma unroll
        for (int e = 0; e < 2; ++e) {
            const int d = 2 * h + e;
            const int tglob = t0 + i0 + d;
            // t>=15 guarantees |z| <= 15/sqrt(16) = 3.75; lv >= log(1e-6) always
            fp[e] = (!SLOW) && (tglob >= 15) && (fabsf(zf[d]) <= 3.9f) && (lvf[d] <= 3.9f);
            float fz = (zf[d] - ZMINF) * ZSCLF;
            float fv = (lvf[d] - VMINF) * VSCLF;
            fz = fminf(fmaxf(fz, 0.f), 510.0f);
            fv = fminf(fmaxf(fv, 0.f), 254.0f);
            const int zi = (int)fz, vi = (int)fv;
            az[e] = fz - (float)zi;
            av[e] = fv - (float)vi;
            const int cidx = vi * NZ + zi;       // [vi][zi] layout
            if (!SLOW) {
                q0[e] = tb4[cidx];               // corners (zi, vi/vi+1)
                q1[e] = tb4[cidx + 1];           // corners (zi+1, vi/vi+1) -- adjacent
            }
        }
        #pragma unroll
        for (int e = 0; e < 2; ++e) {
            const int d = 2 * h + e;
            float w0, w1, w2, w3;
            if (fp[e]) {
                const float avv = av[e], azz = az[e];
                const uint4 a0 = q0[e], a1 = q1[e];
                const float c00 = fmaf(avv, hlo(a0.z) - hlo(a0.x), hlo(a0.x));
                const float c01 = fmaf(avv, hhi(a0.z) - hhi(a0.x), hhi(a0.x));
                const float c02 = fmaf(avv, hlo(a0.w) - hlo(a0.y), hlo(a0.y));
                const float c03 = fmaf(avv, hhi(a0.w) - hhi(a0.y), hhi(a0.y));
                const float c10 = fmaf(avv, hlo(a1.z) - hlo(a1.x), hlo(a1.x));
                const float c11 = fmaf(avv, hhi(a1.z) - hhi(a1.x), hhi(a1.x));
                const float c12 = fmaf(avv, hlo(a1.w) - hlo(a1.y), hlo(a1.y));
                const float c13 = fmaf(avv, hhi(a1.w) - hhi(a1.y), hhi(a1.y));
                w0 = fmaf(azz, c10 - c00, c00);
                w1 = fmaf(azz, c11 - c01, c01);
                w2 = fmaf(azz, c12 - c02, c02);
                w3 = fmaf(azz, c13 - c03, c03);
            } else {
                float wv5[5];
                mlp_w_fast(zf[d], lvf[d], W1, b1, W2, b2, wv5);
                w0 = wv5[0]; w1 = wv5[1]; w2 = wv5[2]; w3 = wv5[3];
            }
            wg0[d] = w0; wg1[d] = w1; wg2[d] = w2; wg3[d] = w3;
        }
    }

    // ---- conv via MFMA: 13 k-steps over 5 sigmas ----
    const int fbase[NS] = {0, 2, 4, 6, 9};
    const int ksn[NS]   = {2, 2, 2, 3, 4};
    const int RA[NS]    = {16, 16, 24, 40, 56};
    f32x4 acc[NS];
    #pragma unroll
    for (int s = 0; s < NS; ++s) acc[s] = (f32x4){0.f, 0.f, 0.f, 0.f};
    #pragma unroll
    for (int s = 0; s < NS; ++s) {
        #pragma unroll
        for (int kk = 0; kk < ksn[s]; ++kk) {
            const bf16x8 A = *reinterpret_cast<const bf16x8*>(&afr4[(fbase[s] + kk) * 64 + lane]);
            const int tof = 16 * wv - RA[s] + 32 * kk + RMX + 8 * g;
            const bf16x8 B = *reinterpret_cast<const bf16x8*>(&sxT[i16 * SXT_LD + tof]);
            acc[s] = __builtin_amdgcn_mfma_f32_16x16x32_bf16(A, B, acc[s], 0, 0, 0);
        }
    }

    // ---- blend + store ----
    const int c = c0 + i16;
    #pragma unroll
    for (int d = 0; d < 4; ++d) {
        const int tglob = t0 + i0 + d;
        const float y4 = acc[4][d];
        float res = y4;
        res = fmaf(wg0[d], acc[0][d] - y4, res);
        res = fmaf(wg1[d], acc[1][d] - y4, res);
        res = fmaf(wg2[d], acc[2][d] - y4, res);
        res = fmaf(wg3[d], acc[3][d] - y4, res);
        out[((size_t)b * NT + tglob) * NC + c] = res;
    }
}

extern "C" void kernel_launch(void* const* d_in, const int* in_sizes, int n_in,
                              void* d_out, int out_size, void* d_ws, size_t ws_size,
                              hipStream_t stream) {
    const float* x  = (const float*)d_in[0];
    const float* W1 = (const float*)d_in[1];
    const float* b1 = (const float*)d_in[2];
    const float* W2 = (const float*)d_in[3];
    const float* b2 = (const float*)d_in[4];
    float* out = (float*)d_out;
    unsigned short* afr = (unsigned short*)d_ws;              // 13312 B used
    unsigned int* tbl = (unsigned int*)((char*)d_ws + FRAG_BYTES);
    const int build_tbl = (ws_size >= WS_NEED) ? 1 : 0;

    init_all_kernel<<<1 + (NZ * NV) / 256, 256, 0, stream>>>(W1, b1, W2, b2, afr, tbl, build_tbl);
    if (build_tbl) {
        fused8_kernel<false><<<4 * NB * (NT / TTILE), 256, 0, stream>>>(
            x, W1, b1, W2, b2, (const uint4*)afr, (const uint4*)tbl, out);
    } else {
        fused8_kernel<true><<<4 * NB * (NT / TTILE), 256, 0, stream>>>(
            x, W1, b1, W2, b2, (const uint4*)afr, (const uint4*)tbl, out);
    }
}